// Round 19
// baseline (225.509 us; speedup 1.0000x reference)
//
#include <hip/hip_runtime.h>
#include <cstdint>
#include <cstddef>

typedef __attribute__((ext_vector_type(4))) float f32x4;
typedef __attribute__((ext_vector_type(16))) float f32x16;
typedef __attribute__((ext_vector_type(8))) short short8;
typedef __attribute__((ext_vector_type(4))) short s16x4;
typedef __attribute__((ext_vector_type(2))) int int2v;
typedef unsigned short u16;

#define DEVINL static __device__ __forceinline__
#define MFMA32(A,B,C) __builtin_amdgcn_mfma_f32_32x32x16_bf16(A,B,C,0,0,0)

constexpr int NBATCH = 4;
constexpr int NSEQ   = 1024;
constexpr int NDIM   = 512;
constexpr int NHEAD  = 8;
constexpr int NDH    = 64;
constexpr int NMLP   = 2048;
constexpr int NROWS  = NBATCH * NSEQ;   // 4096
constexpr int NBLKC  = 32;
constexpr int NBH    = NBATCH * NHEAD;  // 32
constexpr int NQKV   = 1664;            // 1536 qkv + 24 gates + 104 pad

DEVINL float b2f(u16 u) { union { unsigned u; float f; } x; x.u = ((unsigned)u) << 16; return x.f; }
DEVINL u16 f2b(float v) {
    union { float f; unsigned u; } x; x.f = v;
    unsigned r = x.u + 0x7fff + ((x.u >> 16) & 1);
    return (u16)(r >> 16);
}
DEVINL float fastrcp(float x) { float r; asm("v_rcp_f32 %0, %1" : "=v"(r) : "v"(x)); return r; }

DEVINL void gload16(const void* g, void* l)
{
    __builtin_amdgcn_global_load_lds(
        (const __attribute__((address_space(1))) void*)g,
        (__attribute__((address_space(3))) void*)l, 16, 0, 0);
}

// ---------------- LayerNorm -> bf16 ----------------
__global__ void __launch_bounds__(256) ln_kernel(const float* __restrict__ x,
    const float* __restrict__ gg, const float* __restrict__ bb, u16* __restrict__ out)
{
    int row = blockIdx.x * 4 + (threadIdx.x >> 6);
    int lane = threadIdx.x & 63;
    const float* xr = x + (size_t)row * NDIM + lane * 8;
    f32x4 a = *(const f32x4*)xr;
    f32x4 c = *(const f32x4*)(xr + 4);
    float xv[8] = { a[0], a[1], a[2], a[3], c[0], c[1], c[2], c[3] };
    float s = 0.f, s2 = 0.f;
    #pragma unroll
    for (int i = 0; i < 8; ++i) { s += xv[i]; s2 += xv[i] * xv[i]; }
    #pragma unroll
    for (int d = 1; d < 64; d <<= 1) { s += __shfl_xor(s, d); s2 += __shfl_xor(s2, d); }
    float mean = s * (1.f / NDIM);
    float var = s2 * (1.f / NDIM) - mean * mean;
    float rstd = rsqrtf(var + 1e-5f);
    const float* gp = gg + lane * 8;
    const float* bp = bb + lane * 8;
    short8 o;
    #pragma unroll
    for (int i = 0; i < 8; ++i)
        o[i] = (short)f2b((xv[i] - mean) * rstd * gp[i] + bp[i]);
    *(short8*)(out + (size_t)row * NDIM + lane * 8) = o;
}

// ---------------- one-shot weight setup ----------------
__global__ void __launch_bounds__(256) setup_weights(
    const float* __restrict__ Wq, const float* __restrict__ Wk, const float* __restrict__ Wv,
    const float* __restrict__ Wg, const float* __restrict__ Wo,
    const float* __restrict__ W1, const float* __restrict__ W2,
    u16* __restrict__ wqkvT, u16* __restrict__ woT,
    u16* __restrict__ w1T, u16* __restrict__ w2T)
{
    int j = blockIdx.x;
    if (j >= 6144) {               // Wg fill: 8 jobs of 32 rows x 512 cols
        int j5 = j - 6144, l = j5 >> 2, chunk = j5 & 3;
        u16* d2 = wqkvT + (size_t)l * NQKV * 512 + (size_t)(1536 + chunk * 32) * 512;
        const float* src = Wg + (size_t)l * 512 * 24;
        for (int e = threadIdx.x; e < 16384; e += 256) {
            int r = chunk * 32 + (e >> 9), k = e & 511;
            d2[(size_t)(e >> 9) * 512 + k] = (r < 24) ? f2b(src[(size_t)k * 24 + r]) : (u16)0;
        }
        return;
    }
    __shared__ float tile[32][33];
    const float* W; u16* dst; int K, Nc, bx, by;
    if (j < 1536) {
        int z = j >> 8, t = j & 255, l = z / 3, wsel = z % 3;
        W = (wsel == 0 ? Wq : (wsel == 1 ? Wk : Wv)) + (size_t)l * 262144;
        dst = wqkvT + (size_t)l * NQKV * 512 + (size_t)wsel * 262144;
        K = 512; Nc = 512; bx = t & 15; by = t >> 4;
    } else if (j < 2048) {
        int j2 = j - 1536, z = j2 >> 8, t = j2 & 255;
        W = Wo + (size_t)z * 262144; dst = woT + (size_t)z * 262144;
        K = 512; Nc = 512; bx = t & 15; by = t >> 4;
    } else if (j < 4096) {
        int j3 = j - 2048, z = j3 >> 10, t = j3 & 1023;
        W = W1 + (size_t)z * 1048576; dst = w1T + (size_t)z * 1048576;
        K = 512; Nc = 2048; bx = t & 63; by = t >> 6;
    } else {
        int j4 = j - 4096, z = j4 >> 10, t = j4 & 1023;
        W = W2 + (size_t)z * 1048576; dst = w2T + (size_t)z * 1048576;
        K = 2048; Nc = 512; bx = t & 15; by = t >> 4;
    }
    int tx = threadIdx.x & 31, ty = threadIdx.x >> 5;
    int n0 = bx * 32, k0 = by * 32;
    #pragma unroll
    for (int r = 0; r < 4; ++r)
        tile[ty * 4 + r][tx] = W[(size_t)(k0 + ty * 4 + r) * Nc + n0 + tx];
    __syncthreads();
    #pragma unroll
    for (int r = 0; r < 4; ++r)
        dst[(size_t)(n0 + ty * 4 + r) * K + k0 + tx] = f2b(tile[tx][ty * 4 + r]);
}

// ---------------- bf16 MFMA GEMM (EP_QKV also emits pooled kc16/vct16) ----------------
// NB = number of LDS buffers (pipeline depth = NB-1); NB=4 only fits 64x64 tiles.
enum { EP_QKV = 0, EP_GELU = 1, EP_RES = 2 };

template<int BM, int BN, int BK, int KT, int NB, int EPIL>
__global__ void __launch_bounds__(256) gemm_k(
    const u16* __restrict__ A, const u16* __restrict__ BT,
    int M, int Nc,
    const float* __restrict__ bias,
    const float* __restrict__ resin,     // EP_RES: residual input (may == resout)
    float* __restrict__ resout,          // EP_RES: output; EP_QKV: gates out
    u16* __restrict__ outb,
    u16* __restrict__ q16, u16* __restrict__ k16, u16* __restrict__ vt16,
    u16* __restrict__ kc16 = nullptr, u16* __restrict__ vct16 = nullptr)
{
    constexpr int NT = KT / BK;
    constexpr int NK = BK / 32;
    constexpr int RB = BK * 2;
    constexpr int RMSK = (BK == 64) ? 7 : 3;
    constexpr int LA = BM * BK / 2048;
    constexpr int LBD = BN * BK / 2048;
    constexpr int LB = LA + LBD;
    constexpr int DEPTH = NB - 1;          // stages in flight beyond current
    constexpr int WM = BM / 2, WN = BN / 2;
    constexpr int MI = WM / 16, NI = WN / 16;
    __shared__ u16 As[NB][BM][BK];
    __shared__ u16 Bs[NB][BN][BK];
    const int tid = threadIdx.x;
    const int lane = tid & 63;
    const int wid = tid >> 6;
    const int wm = wid >> 1, wn = wid & 1;
    const int gx = gridDim.x;
    const int nblk = gx * gridDim.y;
    const int id = blockIdx.y * gx + blockIdx.x;
    const int sid = (id & 7) * (nblk >> 3) + (id >> 3);
    const int rowBase = (sid / gx) * BM;
    const int colBase = (sid % gx) * BN;
    const int fr = lane & 15;
    const int kg = lane >> 4;

    auto stage = [&](int buf, int t) {
        const size_t k0 = (size_t)t * BK;
        char* aL = (char*)&As[buf][0][0];
        #pragma unroll
        for (int p = 0; p < LA; ++p) {
            int idx = p * 256 + tid;
            int row = idx / (BK / 8);
            int ob = (idx % (BK / 8)) * 16;
            int sw = ob ^ ((row & RMSK) << 4);
            gload16((const char*)(A + (size_t)(rowBase + row) * KT + k0) + sw, aL + idx * 16);
        }
        char* bL = (char*)&Bs[buf][0][0];
        #pragma unroll
        for (int p = 0; p < LBD; ++p) {
            int idx = p * 256 + tid;
            int row = idx / (BK / 8);
            int ob = (idx % (BK / 8)) * 16;
            int sw = ob ^ ((row & RMSK) << 4);
            gload16((const char*)(BT + (size_t)(colBase + row) * KT + k0) + sw, bL + idx * 16);
        }
    };

    #pragma unroll
    for (int p = 0; p < DEPTH; ++p) stage(p, p);
    f32x4 acc[MI][NI] = {};
    for (int t = 0; t < NT; ++t) {
        const int rem = NT - 1 - t;                       // stages still in flight after this
        const int inflight = rem < DEPTH - 1 ? rem : DEPTH - 1;
        if (inflight == 0)      asm volatile("s_waitcnt vmcnt(0)" ::: "memory");
        else if (inflight == 1) asm volatile("s_waitcnt vmcnt(%0)" :: "n"(LB) : "memory");
        else                    asm volatile("s_waitcnt vmcnt(%0)" :: "n"(2 * LB) : "memory");
        __builtin_amdgcn_s_barrier();
        if (t + DEPTH < NT) stage((t + DEPTH) % NB, t + DEPTH);
        const int cb = t % NB;
        const char* aB = (const char*)&As[cb][0][0];
        const char* bB = (const char*)&Bs[cb][0][0];
        #pragma unroll
        for (int kk = 0; kk < NK; ++kk) {
            short8 af[MI], bfr[NI];
            #pragma unroll
            for (int i = 0; i < MI; ++i) {
                int row = wm * WM + i * 16 + fr;
                af[i] = *(const short8*)(aB + row * RB + ((kk * 64 + kg * 16) ^ ((row & RMSK) << 4)));
            }
            #pragma unroll
            for (int j = 0; j < NI; ++j) {
                int row = wn * WN + j * 16 + fr;
                bfr[j] = *(const short8*)(bB + row * RB + ((kk * 64 + kg * 16) ^ ((row & RMSK) << 4)));
            }
            #pragma unroll
            for (int i = 0; i < MI; ++i)
                #pragma unroll
                for (int j = 0; j < NI; ++j)
                    acc[i][j] = __builtin_amdgcn_mfma_f32_16x16x32_bf16(af[i], bfr[j], acc[i][j], 0, 0, 0);
        }
    }

    #pragma unroll
    for (int i = 0; i < MI; ++i) {
        #pragma unroll
        for (int j = 0; j < NI; ++j) {
            int col = colBase + wn * WN + j * 16 + fr;
            if constexpr (EPIL == EP_QKV) {
                int which = col >> 9;
                int row0 = rowBase + wm * WM + i * 16 + kg * 4;
                if (which >= 3) {
                    int c2 = col - 1536;
                    if (c2 < 24) {
                        #pragma unroll
                        for (int rr = 0; rr < 4; ++rr) {
                            float xg = acc[i][j][rr] + bias[c2];
                            resout[(size_t)(row0 + rr) * 24 + c2] =
                                fastrcp(1.f + exp2f(-1.4426950409f * xg));
                        }
                    }
                } else {
                    int c = col & 511;
                    int hh = c >> 6, dh = c & 63;
                    int bb2 = row0 >> 10, n0 = row0 & 1023;
                    size_t bh2 = (size_t)(bb2 * NHEAD + hh) * 65536;
                    if (which == 2) {
                        s16x4 pk;
                        #pragma unroll
                        for (int rr = 0; rr < 4; ++rr) pk[rr] = (short)f2b(acc[i][j][rr]);
                        *(s16x4*)&vt16[bh2 + (size_t)dh * NSEQ + n0] = pk;
                    } else {
                        u16* dst = (which ? k16 : q16) + bh2 + (size_t)n0 * NDH + dh;
                        float scl = which ? 1.f : 0.18033688f;   // q: DH^-0.5 * log2(e)
                        #pragma unroll
                        for (int rr = 0; rr < 4; ++rr) dst[rr * NDH] = f2b(acc[i][j][rr] * scl);
                    }
                }
            } else {
                #pragma unroll
                for (int rr = 0; rr < 4; ++rr) {
                    int row = rowBase + wm * WM + i * 16 + kg * 4 + rr;
                    float val = acc[i][j][rr];
                    if constexpr (EPIL == EP_GELU) {
                        float t = val + bias[col];
                        float u = t + 0.044715f * t * t * t;
                        float gs = fastrcp(1.f + exp2f(-2.3022083f * u));
                        outb[(size_t)row * Nc + col] = f2b(t * gs);
                    } else {
                        size_t o = (size_t)row * Nc + col;
                        resout[o] = resin[o] + val + bias[col];
                    }
                }
            }
        }
    }

    // fused block-mean pooling of K and V (per wave: rows cover exactly one 32-row block)
    if constexpr (EPIL == EP_QKV) {
        const int m = ((rowBase & 1023) >> 5) + wm;
        const int bb2 = rowBase >> 10;
        #pragma unroll
        for (int j = 0; j < NI; ++j) {
            int col = colBase + wn * WN + j * 16 + fr;
            int which = col >> 9;
            if (which == 1 || which == 2) {
                float ps = 0.f;
                #pragma unroll
                for (int i = 0; i < MI; ++i)
                    #pragma unroll
                    for (int rr = 0; rr < 4; ++rr) ps += acc[i][j][rr];
                ps += __shfl_xor(ps, 16);
                ps += __shfl_xor(ps, 32);
                if (kg == 0) {
                    int c = col & 511, hh = c >> 6, dh = c & 63;
                    size_t bhp = (size_t)(bb2 * NHEAD + hh) * 2048;
                    float mval = ps * (1.f / 32.f);
                    if (which == 1) kc16[bhp + m * 64 + dh] = f2b(mval);
                    else            vct16[bhp + (size_t)dh * 32 + m] = f2b(mval);
                }
            }
        }
    }
}

DEVINL unsigned cvtpk(float lo, float hi_)
{
    unsigned t;
    asm("v_cvt_pk_bf16_f32 %0, %1, %2" : "=v"(t) : "v"(lo), "v"(hi_));
    return t;
}

DEVINL void plswap(unsigned& a, unsigned& b)
{
#if __has_builtin(__builtin_amdgcn_permlane32_swap)
    int2v r = __builtin_amdgcn_permlane32_swap((int)a, (int)b, false, false);
    a = (unsigned)r[0]; b = (unsigned)r[1];
#else
    asm("v_permlane32_swap_b32 %0, %1" : "+v"(a), "+v"(b));
#endif
}

DEVINL void packswap(const float* e, unsigned selmask, short8& pb0, short8& pb1)
{
    unsigned w[8];
    #pragma unroll
    for (int i = 0; i < 8; ++i) w[i] = cvtpk(e[2 * i], e[2 * i + 1]) & selmask;
    plswap(w[0], w[2]); plswap(w[1], w[3]);
    plswap(w[4], w[6]); plswap(w[5], w[7]);
    union { unsigned u[4]; short8 s; } c0, c1;
    c0.u[0] = w[0]; c0.u[1] = w[1]; c0.u[2] = w[2]; c0.u[3] = w[3];
    c1.u[0] = w[4]; c1.u[1] = w[5]; c1.u[2] = w[6]; c1.u[3] = w[7];
    pb0 = c0.s; pb1 = c1.s;
}

template<int R0>
DEVINL unsigned rank4(const f32x16& sc_, const float* po, int hi)
{
    unsigned bits = 0;
    #pragma unroll
    for (int k = 0; k < 4; ++k) {
        const int r = R0 + k;
        const int krr = (r & 3) + 8 * (r >> 2);
        const float sr = sc_[r];
        int cnt = 0;
        #pragma unroll
        for (int j = 0; j < 16; ++j) {
            const int krj = (j & 3) + 8 * (j >> 2);
            if (j != r) cnt += (sc_[j] > sr || (sc_[j] == sr && krj < krr)) ? 1 : 0;
            const bool pless = (hi == 0) ? (krj + 4 < krr) : (krj < krr + 4);
            cnt += (po[j] > sr || (po[j] == sr && pless)) ? 1 : 0;
        }
        if (cnt < 8) bits |= 1u << (krr + 4 * hi);
    }
    return bits;
}

// ---------------- MFMA attention (R16 known-good): 4 waves, each 8 kv-blocks x full d,
// wave-private DOUBLE-buffered LDS staging (64KB), launch_bounds(256,2). ----------------
__global__ void __launch_bounds__(256, 2) attn_mfma(
    const u16* __restrict__ qb, const u16* __restrict__ kb, const u16* __restrict__ vt,
    const u16* __restrict__ kc16, const u16* __restrict__ vct16,
    const float* __restrict__ gates, u16* __restrict__ att)
{
    __shared__ __align__(16) char smem[65536];
    unsigned* selb_lds = (unsigned*)(smem + 32768);   // overlaps buf1 (dead before buf1 use)
    const int tid = threadIdx.x;
    const int wid = tid >> 6;
    const int lane = tid & 63;
    const int qc = lane & 31, hi = lane >> 5;
    const int g = blockIdx.x;                  // 0..1023
    const int xcd = g & 7, ii = g >> 3;        // ii 0..127
    const int bh = xcd * 4 + (ii >> 5);
    const int qt = ii & 31;
    const int qrow = qt * 32 + qc;
    if (tid < 32) selb_lds[tid] = 0u;
    const u16* Q = qb + (size_t)bh * 65536;
    const char* Kby = (const char*)(kb + (size_t)bh * 65536);
    const char* Vby = (const char*)(vt + (size_t)bh * 65536);

    const int l16 = lane * 16;
    auto stage = [&](int buf, int blk) {
        char* base = smem + buf * 32768 + wid * 4096;
        #pragma unroll
        for (int i = 0; i < 4; ++i) {
            int o = i * 1024 + l16;
            int so = o ^ (((o >> 7) & 7) << 4);
            gload16(Kby + (size_t)blk * 4096 + so, base + o);
        }
        #pragma unroll
        for (int i = 0; i < 4; ++i) {
            int o = i * 1024 + l16;
            int row = o >> 6;
            int colb = (o & 63) ^ ((row & 3) << 4);
            gload16(Vby + (size_t)row * 2048 + blk * 64 + colb, base + 16384 + o);
        }
    };
    const int blo = wid * 8;
    stage(0, blo);

    short8 qf[4];
    #pragma unroll
    for (int ks = 0; ks < 4; ++ks)
        qf[ks] = *(const short8*)&Q[(size_t)qrow * 64 + ks * 16 + hi * 8];
    const int b = bh >> 3, h = bh & 7;
    const float* grow = gates + (size_t)(b * 1024 + qrow) * 24 + h * 3;
    const float g0 = grow[0], g1 = grow[1], g2 = grow[2];

    const u16* Kc = kc16 + (size_t)bh * 2048;
    const u16* Vc = vct16 + (size_t)bh * 2048;
    f32x16 sc_ = {};
    #pragma unroll
    for (int ks = 0; ks < 4; ++ks) {
        short8 kcf = *(const short8*)&Kc[qc * 64 + ks * 16 + hi * 8];
        sc_ = MFMA32(kcf, qf[ks], sc_);
    }
    float po[16];
    #pragma unroll
    for (int r = 0; r < 16; ++r) po[r] = __shfl_xor(sc_[r], 32);
    unsigned bits;
    switch (wid) {
        case 0:  bits = rank4<0>(sc_, po, hi); break;
        case 1:  bits = rank4<4>(sc_, po, hi); break;
        case 2:  bits = rank4<8>(sc_, po, hi); break;
        default: bits = rank4<12>(sc_, po, hi); break;
    }
    __syncthreads();
    atomicOr(&selb_lds[qc], bits);

    // compressed branch: wave 0 -> d 0..31, wave 1 -> d 32..63
    f32x16 aC = {};
    float denc = 1.f;
    if (wid < 2) {
        float ec[16]; float dsum = 0.f;
        #pragma unroll
        for (int r = 0; r < 16; ++r) { ec[r] = exp2f(sc_[r]); dsum += ec[r]; }
        denc = dsum + __shfl_xor(dsum, 32);
        short8 pc0, pc1;
        packswap(ec, 0xFFFFFFFFu, pc0, pc1);
        const u16* Vch = Vc + (wid * 32 + qc) * 32 + hi * 8;
        short8 vcA = *(const short8*)&Vch[0];
        short8 vcB = *(const short8*)&Vch[16];
        aC = MFMA32(vcA, pc0, aC);
        aC = MFMA32(vcB, pc1, aC);
    }
    __syncthreads();
    const unsigned mask = selb_lds[qc];

    // ---- selection + window: 8 blocks per wave, full d ----
    f32x16 aS0 = {}, aS1 = {}, aW0 = {}, aW1 = {};
    float denS = 0.f, denW = 0.f;
    const int wlo = qt > 0 ? qt - 1 : 0;
    const int whi = qt < 31 ? qt + 1 : 31;

    int kra[4];
    #pragma unroll
    for (int ks = 0; ks < 4; ++ks)
        kra[ks] = wid * 4096 + ((qc * 128 + ks * 32 + hi * 16) ^ ((qc & 7) << 4));
    const int vbase = wid * 4096 + 16384;
    const int v00o = vbase + ((qc * 64 + hi * 16) ^ ((qc & 3) << 4));
    const int v01o = vbase + ((qc * 64 + 32 + hi * 16) ^ ((qc & 3) << 4));
    const int v10o = vbase + ((2048 + qc * 64 + hi * 16) ^ ((qc & 3) << 4));
    const int v11o = vbase + ((2048 + qc * 64 + 32 + hi * 16) ^ ((qc & 3) << 4));

    for (int t = 0; t < 8; ++t) {
        const int blk = blo + t;
        const char* base = smem + (t & 1) * 32768;
        if (t < 7) {
            stage((t + 1) & 1, blk + 1);
            asm volatile("s_waitcnt vmcnt(8)" ::: "memory");
        } else {
            asm volatile("s_waitcnt vmcnt(0)" ::: "memory");
        }
        short8 kf[4];
        #pragma unroll
        for (int ks = 0; ks < 4; ++ks)
            kf[ks] = *(const short8*)(base + kra[ks]);
        __builtin_amdgcn_s_setprio(1);
        f32x16 s = {};
        #pragma unroll
        for (int ks = 0; ks < 4; ++ks)
            s = MFMA32(kf[ks], qf[ks], s);
        __builtin_amdgcn_s_setprio(0);
        float e[16];
        #pragma unroll
        for (int r = 0; r < 16; ++r) e[r] = exp2f(s[r]);

        short8 v00 = *(const short8*)(base + v00o);
        short8 v01 = *(const short8*)(base + v01o);
        short8 v10 = *(const short8*)(base + v10o);
        short8 v11 = *(const short8*)(base + v11o);

        const bool selb = (mask >> blk) & 1u;
        const unsigned selm = selb ? 0xFFFFFFFFu : 0u;
        {
            float tt = 0.f;
            #pragma unroll
            for (int r = 0; r < 16; ++r) tt += e[r];
            denS += selb ? tt : 0.f;
        }
        short8 pb0, pb1;
        packswap(e, selm, pb0, pb1);
        __builtin_amdgcn_s_setprio(1);
        aS0 = MFMA32(v00, pb0, aS0);
        aS0 = MFMA32(v01, pb1, aS0);
        aS1 = MFMA32(v10, pb0, aS1);
        aS1 = MFMA32(v11, pb1, aS1);
        __builtin_amdgcn_s_setprio(0);

        if (blk >= wlo && blk <= whi) {
            float ew[16];
            float tt = 0.f;
            #pragma unroll
            for (int r = 0; r < 16; ++r) {
                int kr = (r & 3) + 8 * (r >> 2) + 4 * hi;
                int dd = blk * 32 + kr - qrow;
                ew[r] = (dd >= -32 && dd <= 32) ? e[r] : 0.f;
                tt += ew[r];
            }
            denW += tt;
            short8 pw0, pw1;
            packswap(ew, 0xFFFFFFFFu, pw0, pw1);
            aW0 = MFMA32(v00, pw0, aW0);
            aW0 = MFMA32(v01, pw1, aW0);
            aW1 = MFMA32(v10, pw0, aW1);
            aW1 = MFMA32(v11, pw1, aW1);
        }
    }
    __syncthreads();

    // ---- cross-wave combine over staging LDS (stride 85) ----
    float* cmb = (float*)smem;
    if (wid > 0) {
        float* dst = cmb + (size_t)(wid - 1) * (64 * 85) + lane * 85;
        #pragma unroll
        for (int i = 0; i < 16; ++i) { dst[i] = aS0[i]; dst[16 + i] = aS1[i]; }
        #pragma unroll
        for (int i = 0; i < 16; ++i) { dst[32 + i] = aW0[i]; dst[48 + i] = aW1[i]; }
        dst[64] = denS; dst[65] = denW;
        if (wid == 1) {
            #pragma unroll
            for (int i = 0; i < 16; ++i) dst[66 + i] = aC[i];
        }
    }
    __syncthreads();
    if (wid == 0) {
        #pragma unroll
        for (int w = 1; w < 4; ++w) {
            const float* src = cmb + (size_t)(w - 1) * (64 * 85) + lane * 85;
            #pragma unroll
            for (int i = 0; i < 16; ++i) { aS0[i] += src[i]; aS1[i] += src[16 + i]; }
            #pragma unroll
            for (int i = 0; i < 16; ++i) { aW0[i] += src[32 + i]; aW1[i] += src[48 + i]; }
            denS += src[64]; denW += src[65];
        }
        f32x16 aC1;
        const float* s1 = cmb + lane * 85;
        #pragma unroll
        for (int i = 0; i < 16; ++i) aC1[i] = s1[66 + i];
        denS += __shfl_xor(denS, 32);
        denW += __shfl_xor(denW, 32);
        const float rc = g0 / denc, rs = g1 / denS, rw = g2 / denW;
        u16* op = att + (size_t)(b * 1024 + qrow) * NDIM + h * 64;
        #pragma unroll
        for (int c4 = 0; c4 < 4; ++c4) {
            int d0 = c4 * 8 + hi * 4;
            s16x4 w0, w1;
            #pragma unroll
            for (int j = 0; j < 4; ++j) {
                w0[j] = (short)f2b(rc * aC[c4 * 4 + j]  + rs * aS0[c4 * 4 + j] + rw * aW0[c4 * 4 + j]);
                w1[j] = (short)f2b(rc * aC1[c4 * 4 + j] + rs * aS1[c4 * 4 + j] + rw * aW1[c4 * 4 + j]);
            }
            *(s16x4*)&op[d0] = w0;
            *(s16x4*)&op[d0 + 32] = w1;
        }
    }
}

// ---------------- host ----------------
extern "C" void kernel_launch(void* const* d_in, const int* in_sizes, int n_in,
                              void* d_out, int out_size, void* d_ws, size_t ws_size,
                              hipStream_t stream)
{
    const float* x0    = (const float*)d_in[0];
    const float* ln1_g = (const float*)d_in[1];
    const float* ln1_b = (const float*)d_in[2];
    const float* Wq    = (const float*)d_in[3];
    const float* Wk    = (const float*)d_in[4];
    const float* Wv    = (const float*)d_in[5];
    const float* Wg    = (const float*)d_in[6];
    const float* bg    = (const float*)d_in[7];
    const float* Wo    = (const float*)d_in[8];
    const float* bo    = (const float*)d_in[9];
    const float* ln2_g = (const float*)d_in[10];
    const float* ln2_b = (const float*)d_in[11];
    const float* W1    = (const float*)d_in[12];
    const float* b1    = (const float*)d_in[13];
    const float* W2    = (const float*)d_in[14];
    const float* b2    = (const float*)d_in[15];
    float* xo = (float*)d_out;

    char* w = (char*)d_ws;
    auto alloc = [&](size_t bytes) { char* p = w; w += (bytes + 255) & ~(size_t)255; return p; };
    u16*   hbf   = (u16*)  alloc((size_t)NROWS * NDIM * 2);
    u16*   qb    = (u16*)  alloc((size_t)NBH * NSEQ * NDH * 2);
    u16*   kb    = (u16*)  alloc((size_t)NBH * NSEQ * NDH * 2);
    u16*   vt    = (u16*)  alloc((size_t)NBH * NDH * NSEQ * 2);
    u16*   att   = (u16*)  alloc((size_t)NROWS * NDIM * 2);
    float* gates = (float*)alloc((size_t)NROWS * NHEAD * 3 * 4);
    u16*   kc16  = (u16*)  alloc((size_t)NBH * NBLKC * NDH * 2);
    u16*   vct16 = (u16*)  alloc((size_t)NBH * NDH * NBLKC * 2);
    u16*   wqkvT = (u16*)  alloc((size_t)2 * NQKV * 512 * 2);
    u16*   woT   = (u16*)  alloc((size_t)2 * 512 * 512 * 2);
    u16*   w1T   = (u16*)  alloc((size_t)2 * 2048 * 512 * 2);
    u16*   w2T   = (u16*)  alloc((size_t)2 * 512 * 2048 * 2);
    u16*   mid   = (u16*)qb;

    setup_weights<<<6152, 256, 0, stream>>>(Wq, Wk, Wv, Wg, Wo, W1, W2, wqkvT, woT, w1T, w2T);

    for (int l = 0; l < 2; ++l) {
        const float* xin = (l == 0) ? x0 : xo;   // residual source for this layer's attn block
        ln_kernel<<<NROWS / 4, 256, 0, stream>>>(xin, ln1_g + l * NDIM, ln1_b + l * NDIM, hbf);
        gemm_k<64, 128, 64, 512, 3, EP_QKV><<<dim3(NQKV / 128, NROWS / 64), 256, 0, stream>>>(
            hbf, wqkvT + (size_t)l * NQKV * 512, NROWS, NQKV,
            bg + l * 24, nullptr, gates, nullptr, qb, kb, vt, kc16, vct16);
        attn_mfma<<<1024, 256, 0, stream>>>(qb, kb, vt, kc16, vct16, gates, att);
        gemm_k<64, 64, 64, 512, 4, EP_RES><<<dim3(512 / 64, NROWS / 64), 256, 0, stream>>>(
            att, woT + (size_t)l * 512 * 512, NROWS, 512,
            bo + l * NDIM, xin, xo, nullptr, nullptr, nullptr, nullptr);
        ln_kernel<<<NROWS / 4, 256, 0, stream>>>(xo, ln2_g + l * NDIM, ln2_b + l * NDIM, hbf);
        gemm_k<64, 128, 64, 512, 3, EP_GELU><<<dim3(2048 / 128, NROWS / 64), 256, 0, stream>>>(
            hbf, w1T + (size_t)l * 2048 * 512, NROWS, 2048,
            b1 + l * NMLP, nullptr, nullptr, mid, nullptr, nullptr, nullptr);
        gemm_k<64, 64, 64, 2048, 4, EP_RES><<<dim3(512 / 64, NROWS / 64), 256, 0, stream>>>(
            mid, w2T + (size_t)l * 512 * 2048, NROWS, 512,
            b2 + l * NDIM, xo, xo, nullptr, nullptr, nullptr, nullptr);
    }
}

// Round 20
// 222.461 us; speedup vs baseline: 1.0137x; 1.0137x over previous
//
#include <hip/hip_runtime.h>
#include <cstdint>
#include <cstddef>

typedef __attribute__((ext_vector_type(4))) float f32x4;
typedef __attribute__((ext_vector_type(16))) float f32x16;
typedef __attribute__((ext_vector_type(8))) short short8;
typedef __attribute__((ext_vector_type(4))) short s16x4;
typedef __attribute__((ext_vector_type(2))) int int2v;
typedef unsigned short u16;

#define DEVINL static __device__ __forceinline__
#define MFMA32(A,B,C) __builtin_amdgcn_mfma_f32_32x32x16_bf16(A,B,C,0,0,0)

constexpr int NBATCH = 4;
constexpr int NSEQ   = 1024;
constexpr int NDIM   = 512;
constexpr int NHEAD  = 8;
constexpr int NDH    = 64;
constexpr int NMLP   = 2048;
constexpr int NROWS  = NBATCH * NSEQ;   // 4096
constexpr int NBLKC  = 32;
constexpr int NBH    = NBATCH * NHEAD;  // 32
constexpr int NQKV   = 1664;            // 1536 qkv + 24 gates + 104 pad

DEVINL float b2f(u16 u) { union { unsigned u; float f; } x; x.u = ((unsigned)u) << 16; return x.f; }
DEVINL u16 f2b(float v) {
    union { float f; unsigned u; } x; x.f = v;
    unsigned r = x.u + 0x7fff + ((x.u >> 16) & 1);
    return (u16)(r >> 16);
}
DEVINL float fastrcp(float x) { float r; asm("v_rcp_f32 %0, %1" : "=v"(r) : "v"(x)); return r; }

DEVINL void gload16(const void* g, void* l)
{
    __builtin_amdgcn_global_load_lds(
        (const __attribute__((address_space(1))) void*)g,
        (__attribute__((address_space(3))) void*)l, 16, 0, 0);
}

// ---------------- LayerNorm -> bf16 ----------------
__global__ void __launch_bounds__(256) ln_kernel(const float* __restrict__ x,
    const float* __restrict__ gg, const float* __restrict__ bb, u16* __restrict__ out)
{
    int row = blockIdx.x * 4 + (threadIdx.x >> 6);
    int lane = threadIdx.x & 63;
    const float* xr = x + (size_t)row * NDIM + lane * 8;
    f32x4 a = *(const f32x4*)xr;
    f32x4 c = *(const f32x4*)(xr + 4);
    float xv[8] = { a[0], a[1], a[2], a[3], c[0], c[1], c[2], c[3] };
    float s = 0.f, s2 = 0.f;
    #pragma unroll
    for (int i = 0; i < 8; ++i) { s += xv[i]; s2 += xv[i] * xv[i]; }
    #pragma unroll
    for (int d = 1; d < 64; d <<= 1) { s += __shfl_xor(s, d); s2 += __shfl_xor(s2, d); }
    float mean = s * (1.f / NDIM);
    float var = s2 * (1.f / NDIM) - mean * mean;
    float rstd = rsqrtf(var + 1e-5f);
    const float* gp = gg + lane * 8;
    const float* bp = bb + lane * 8;
    short8 o;
    #pragma unroll
    for (int i = 0; i < 8; ++i)
        o[i] = (short)f2b((xv[i] - mean) * rstd * gp[i] + bp[i]);
    *(short8*)(out + (size_t)row * NDIM + lane * 8) = o;
}

// ---------------- one-shot weight setup ----------------
__global__ void __launch_bounds__(256) setup_weights(
    const float* __restrict__ Wq, const float* __restrict__ Wk, const float* __restrict__ Wv,
    const float* __restrict__ Wg, const float* __restrict__ Wo,
    const float* __restrict__ W1, const float* __restrict__ W2,
    u16* __restrict__ wqkvT, u16* __restrict__ woT,
    u16* __restrict__ w1T, u16* __restrict__ w2T)
{
    int j = blockIdx.x;
    if (j >= 6144) {               // Wg fill: 8 jobs of 32 rows x 512 cols
        int j5 = j - 6144, l = j5 >> 2, chunk = j5 & 3;
        u16* d2 = wqkvT + (size_t)l * NQKV * 512 + (size_t)(1536 + chunk * 32) * 512;
        const float* src = Wg + (size_t)l * 512 * 24;
        for (int e = threadIdx.x; e < 16384; e += 256) {
            int r = chunk * 32 + (e >> 9), k = e & 511;
            d2[(size_t)(e >> 9) * 512 + k] = (r < 24) ? f2b(src[(size_t)k * 24 + r]) : (u16)0;
        }
        return;
    }
    __shared__ float tile[32][33];
    const float* W; u16* dst; int K, Nc, bx, by;
    if (j < 1536) {
        int z = j >> 8, t = j & 255, l = z / 3, wsel = z % 3;
        W = (wsel == 0 ? Wq : (wsel == 1 ? Wk : Wv)) + (size_t)l * 262144;
        dst = wqkvT + (size_t)l * NQKV * 512 + (size_t)wsel * 262144;
        K = 512; Nc = 512; bx = t & 15; by = t >> 4;
    } else if (j < 2048) {
        int j2 = j - 1536, z = j2 >> 8, t = j2 & 255;
        W = Wo + (size_t)z * 262144; dst = woT + (size_t)z * 262144;
        K = 512; Nc = 512; bx = t & 15; by = t >> 4;
    } else if (j < 4096) {
        int j3 = j - 2048, z = j3 >> 10, t = j3 & 1023;
        W = W1 + (size_t)z * 1048576; dst = w1T + (size_t)z * 1048576;
        K = 512; Nc = 2048; bx = t & 63; by = t >> 6;
    } else {
        int j4 = j - 4096, z = j4 >> 10, t = j4 & 1023;
        W = W2 + (size_t)z * 1048576; dst = w2T + (size_t)z * 1048576;
        K = 2048; Nc = 512; bx = t & 15; by = t >> 4;
    }
    int tx = threadIdx.x & 31, ty = threadIdx.x >> 5;
    int n0 = bx * 32, k0 = by * 32;
    #pragma unroll
    for (int r = 0; r < 4; ++r)
        tile[ty * 4 + r][tx] = W[(size_t)(k0 + ty * 4 + r) * Nc + n0 + tx];
    __syncthreads();
    #pragma unroll
    for (int r = 0; r < 4; ++r)
        dst[(size_t)(n0 + ty * 4 + r) * K + k0 + tx] = f2b(tile[tx][ty * 4 + r]);
}

// ---------------- bf16 MFMA GEMM (EP_QKV also emits pooled kc16/vct16) ----------------
enum { EP_QKV = 0, EP_GELU = 1, EP_RES = 2 };

template<int BM, int BN, int BK, int KT, int EPIL>
__global__ void __launch_bounds__(256) gemm_k(
    const u16* __restrict__ A, const u16* __restrict__ BT,
    int M, int Nc,
    const float* __restrict__ bias,
    const float* __restrict__ resin,     // EP_RES: residual input (may == resout)
    float* __restrict__ resout,          // EP_RES: output; EP_QKV: gates out
    u16* __restrict__ outb,
    u16* __restrict__ q16, u16* __restrict__ k16, u16* __restrict__ vt16,
    u16* __restrict__ kc16 = nullptr, u16* __restrict__ vct16 = nullptr)
{
    constexpr int NT = KT / BK;
    constexpr int NK = BK / 32;
    constexpr int RB = BK * 2;
    constexpr int RMSK = (BK == 64) ? 7 : 3;
    constexpr int LA = BM * BK / 2048;
    constexpr int LBD = BN * BK / 2048;
    constexpr int LB = LA + LBD;
    constexpr int WM = BM / 2, WN = BN / 2;
    constexpr int MI = WM / 16, NI = WN / 16;
    __shared__ u16 As[3][BM][BK];
    __shared__ u16 Bs[3][BN][BK];
    const int tid = threadIdx.x;
    const int lane = tid & 63;
    const int wid = tid >> 6;
    const int wm = wid >> 1, wn = wid & 1;
    const int gx = gridDim.x;
    const int nblk = gx * gridDim.y;
    const int id = blockIdx.y * gx + blockIdx.x;
    const int sid = (id & 7) * (nblk >> 3) + (id >> 3);
    const int rowBase = (sid / gx) * BM;
    const int colBase = (sid % gx) * BN;
    const int fr = lane & 15;
    const int kg = lane >> 4;

    auto stage = [&](int buf, int t) {
        const size_t k0 = (size_t)t * BK;
        char* aL = (char*)&As[buf][0][0];
        #pragma unroll
        for (int p = 0; p < LA; ++p) {
            int idx = p * 256 + tid;
            int row = idx / (BK / 8);
            int ob = (idx % (BK / 8)) * 16;
            int sw = ob ^ ((row & RMSK) << 4);
            gload16((const char*)(A + (size_t)(rowBase + row) * KT + k0) + sw, aL + idx * 16);
        }
        char* bL = (char*)&Bs[buf][0][0];
        #pragma unroll
        for (int p = 0; p < LBD; ++p) {
            int idx = p * 256 + tid;
            int row = idx / (BK / 8);
            int ob = (idx % (BK / 8)) * 16;
            int sw = ob ^ ((row & RMSK) << 4);
            gload16((const char*)(BT + (size_t)(colBase + row) * KT + k0) + sw, bL + idx * 16);
        }
    };

    stage(0, 0);
    stage(1, 1);
    f32x4 acc[MI][NI] = {};
    int cb = 0, nb = 1, sb = 2;
    for (int t = 0; t < NT; ++t) {
        if (t == NT - 1) asm volatile("s_waitcnt vmcnt(0)" ::: "memory");
        else             asm volatile("s_waitcnt vmcnt(%0)" :: "n"(LB) : "memory");
        __builtin_amdgcn_s_barrier();
        if (t + 2 < NT) stage(sb, t + 2);
        const char* aB = (const char*)&As[cb][0][0];
        const char* bB = (const char*)&Bs[cb][0][0];
        #pragma unroll
        for (int kk = 0; kk < NK; ++kk) {
            short8 af[MI], bfr[NI];
            #pragma unroll
            for (int i = 0; i < MI; ++i) {
                int row = wm * WM + i * 16 + fr;
                af[i] = *(const short8*)(aB + row * RB + ((kk * 64 + kg * 16) ^ ((row & RMSK) << 4)));
            }
            #pragma unroll
            for (int j = 0; j < NI; ++j) {
                int row = wn * WN + j * 16 + fr;
                bfr[j] = *(const short8*)(bB + row * RB + ((kk * 64 + kg * 16) ^ ((row & RMSK) << 4)));
            }
            #pragma unroll
            for (int i = 0; i < MI; ++i)
                #pragma unroll
                for (int j = 0; j < NI; ++j)
                    acc[i][j] = __builtin_amdgcn_mfma_f32_16x16x32_bf16(af[i], bfr[j], acc[i][j], 0, 0, 0);
        }
        int tmp = cb; cb = nb; nb = sb; sb = tmp;
    }

    #pragma unroll
    for (int i = 0; i < MI; ++i) {
        #pragma unroll
        for (int j = 0; j < NI; ++j) {
            int col = colBase + wn * WN + j * 16 + fr;
            if constexpr (EPIL == EP_QKV) {
                int which = col >> 9;
                int row0 = rowBase + wm * WM + i * 16 + kg * 4;
                if (which >= 3) {
                    int c2 = col - 1536;
                    if (c2 < 24) {
                        #pragma unroll
                        for (int rr = 0; rr < 4; ++rr) {
                            float xg = acc[i][j][rr] + bias[c2];
                            resout[(size_t)(row0 + rr) * 24 + c2] =
                                fastrcp(1.f + exp2f(-1.4426950409f * xg));
                        }
                    }
                } else {
                    int c = col & 511;
                    int hh = c >> 6, dh = c & 63;
                    int bb2 = row0 >> 10, n0 = row0 & 1023;
                    size_t bh2 = (size_t)(bb2 * NHEAD + hh) * 65536;
                    if (which == 2) {
                        s16x4 pk;
                        #pragma unroll
                        for (int rr = 0; rr < 4; ++rr) pk[rr] = (short)f2b(acc[i][j][rr]);
                        *(s16x4*)&vt16[bh2 + (size_t)dh * NSEQ + n0] = pk;
                    } else {
                        u16* dst = (which ? k16 : q16) + bh2 + (size_t)n0 * NDH + dh;
                        float scl = which ? 1.f : 0.18033688f;   // q: DH^-0.5 * log2(e)
                        #pragma unroll
                        for (int rr = 0; rr < 4; ++rr) dst[rr * NDH] = f2b(acc[i][j][rr] * scl);
                    }
                }
            } else {
                #pragma unroll
                for (int rr = 0; rr < 4; ++rr) {
                    int row = rowBase + wm * WM + i * 16 + kg * 4 + rr;
                    float val = acc[i][j][rr];
                    if constexpr (EPIL == EP_GELU) {
                        float t = val + bias[col];
                        float u = t + 0.044715f * t * t * t;
                        float gs = fastrcp(1.f + exp2f(-2.3022083f * u));
                        outb[(size_t)row * Nc + col] = f2b(t * gs);
                    } else {
                        size_t o = (size_t)row * Nc + col;
                        resout[o] = resin[o] + val + bias[col];
                    }
                }
            }
        }
    }

    // fused block-mean pooling of K and V (per wave: rows cover exactly one 32-row block)
    if constexpr (EPIL == EP_QKV) {
        const int m = ((rowBase & 1023) >> 5) + wm;
        const int bb2 = rowBase >> 10;
        #pragma unroll
        for (int j = 0; j < NI; ++j) {
            int col = colBase + wn * WN + j * 16 + fr;
            int which = col >> 9;
            if (which == 1 || which == 2) {
                float ps = 0.f;
                #pragma unroll
                for (int i = 0; i < MI; ++i)
                    #pragma unroll
                    for (int rr = 0; rr < 4; ++rr) ps += acc[i][j][rr];
                ps += __shfl_xor(ps, 16);
                ps += __shfl_xor(ps, 32);
                if (kg == 0) {
                    int c = col & 511, hh = c >> 6, dh = c & 63;
                    size_t bhp = (size_t)(bb2 * NHEAD + hh) * 2048;
                    float mval = ps * (1.f / 32.f);
                    if (which == 1) kc16[bhp + m * 64 + dh] = f2b(mval);
                    else            vct16[bhp + (size_t)dh * 32 + m] = f2b(mval);
                }
            }
        }
    }
}

DEVINL unsigned cvtpk(float lo, float hi_)
{
    unsigned t;
    asm("v_cvt_pk_bf16_f32 %0, %1, %2" : "=v"(t) : "v"(lo), "v"(hi_));
    return t;
}

DEVINL void plswap(unsigned& a, unsigned& b)
{
#if __has_builtin(__builtin_amdgcn_permlane32_swap)
    int2v r = __builtin_amdgcn_permlane32_swap((int)a, (int)b, false, false);
    a = (unsigned)r[0]; b = (unsigned)r[1];
#else
    asm("v_permlane32_swap_b32 %0, %1" : "+v"(a), "+v"(b));
#endif
}

DEVINL void packswap(const float* e, unsigned selmask, short8& pb0, short8& pb1)
{
    unsigned w[8];
    #pragma unroll
    for (int i = 0; i < 8; ++i) w[i] = cvtpk(e[2 * i], e[2 * i + 1]) & selmask;
    plswap(w[0], w[2]); plswap(w[1], w[3]);
    plswap(w[4], w[6]); plswap(w[5], w[7]);
    union { unsigned u[4]; short8 s; } c0, c1;
    c0.u[0] = w[0]; c0.u[1] = w[1]; c0.u[2] = w[2]; c0.u[3] = w[3];
    c1.u[0] = w[4]; c1.u[1] = w[5]; c1.u[2] = w[6]; c1.u[3] = w[7];
    pb0 = c0.s; pb1 = c1.s;
}

template<int R0>
DEVINL unsigned rank4(const f32x16& sc_, const float* po, int hi)
{
    unsigned bits = 0;
    #pragma unroll
    for (int k = 0; k < 4; ++k) {
        const int r = R0 + k;
        const int krr = (r & 3) + 8 * (r >> 2);
        const float sr = sc_[r];
        int cnt = 0;
        #pragma unroll
        for (int j = 0; j < 16; ++j) {
            const int krj = (j & 3) + 8 * (j >> 2);
            if (j != r) cnt += (sc_[j] > sr || (sc_[j] == sr && krj < krr)) ? 1 : 0;
            const bool pless = (hi == 0) ? (krj + 4 < krr) : (krj < krr + 4);
            cnt += (po[j] > sr || (po[j] == sr && pless)) ? 1 : 0;
        }
        if (cnt < 8) bits |= 1u << (krr + 4 * hi);
    }
    return bits;
}

// ---------------- MFMA attention (R16 known-good): 4 waves, each 8 kv-blocks x full d,
// wave-private DOUBLE-buffered LDS staging (64KB), launch_bounds(256,2). ----------------
__global__ void __launch_bounds__(256, 2) attn_mfma(
    const u16* __restrict__ qb, const u16* __restrict__ kb, const u16* __restrict__ vt,
    const u16* __restrict__ kc16, const u16* __restrict__ vct16,
    const float* __restrict__ gates, u16* __restrict__ att)
{
    __shared__ __align__(16) char smem[65536];
    unsigned* selb_lds = (unsigned*)(smem + 32768);   // overlaps buf1 (dead before buf1 use)
    const int tid = threadIdx.x;
    const int wid = tid >> 6;
    const int lane = tid & 63;
    const int qc = lane & 31, hi = lane >> 5;
    const int g = blockIdx.x;                  // 0..1023
    const int xcd = g & 7, ii = g >> 3;        // ii 0..127
    const int bh = xcd * 4 + (ii >> 5);
    const int qt = ii & 31;
    const int qrow = qt * 32 + qc;
    if (tid < 32) selb_lds[tid] = 0u;
    const u16* Q = qb + (size_t)bh * 65536;
    const char* Kby = (const char*)(kb + (size_t)bh * 65536);
    const char* Vby = (const char*)(vt + (size_t)bh * 65536);

    const int l16 = lane * 16;
    auto stage = [&](int buf, int blk) {
        char* base = smem + buf * 32768 + wid * 4096;
        #pragma unroll
        for (int i = 0; i < 4; ++i) {
            int o = i * 1024 + l16;
            int so = o ^ (((o >> 7) & 7) << 4);
            gload16(Kby + (size_t)blk * 4096 + so, base + o);
        }
        #pragma unroll
        for (int i = 0; i < 4; ++i) {
            int o = i * 1024 + l16;
            int row = o >> 6;
            int colb = (o & 63) ^ ((row & 3) << 4);
            gload16(Vby + (size_t)row * 2048 + blk * 64 + colb, base + 16384 + o);
        }
    };
    const int blo = wid * 8;
    stage(0, blo);

    short8 qf[4];
    #pragma unroll
    for (int ks = 0; ks < 4; ++ks)
        qf[ks] = *(const short8*)&Q[(size_t)qrow * 64 + ks * 16 + hi * 8];
    const int b = bh >> 3, h = bh & 7;
    const float* grow = gates + (size_t)(b * 1024 + qrow) * 24 + h * 3;
    const float g0 = grow[0], g1 = grow[1], g2 = grow[2];

    const u16* Kc = kc16 + (size_t)bh * 2048;
    const u16* Vc = vct16 + (size_t)bh * 2048;
    f32x16 sc_ = {};
    #pragma unroll
    for (int ks = 0; ks < 4; ++ks) {
        short8 kcf = *(const short8*)&Kc[qc * 64 + ks * 16 + hi * 8];
        sc_ = MFMA32(kcf, qf[ks], sc_);
    }
    float po[16];
    #pragma unroll
    for (int r = 0; r < 16; ++r) po[r] = __shfl_xor(sc_[r], 32);
    unsigned bits;
    switch (wid) {
        case 0:  bits = rank4<0>(sc_, po, hi); break;
        case 1:  bits = rank4<4>(sc_, po, hi); break;
        case 2:  bits = rank4<8>(sc_, po, hi); break;
        default: bits = rank4<12>(sc_, po, hi); break;
    }
    __syncthreads();
    atomicOr(&selb_lds[qc], bits);

    // compressed branch: wave 0 -> d 0..31, wave 1 -> d 32..63
    f32x16 aC = {};
    float denc = 1.f;
    if (wid < 2) {
        float ec[16]; float dsum = 0.f;
        #pragma unroll
        for (int r = 0; r < 16; ++r) { ec[r] = exp2f(sc_[r]); dsum += ec[r]; }
        denc = dsum + __shfl_xor(dsum, 32);
        short8 pc0, pc1;
        packswap(ec, 0xFFFFFFFFu, pc0, pc1);
        const u16* Vch = Vc + (wid * 32 + qc) * 32 + hi * 8;
        short8 vcA = *(const short8*)&Vch[0];
        short8 vcB = *(const short8*)&Vch[16];
        aC = MFMA32(vcA, pc0, aC);
        aC = MFMA32(vcB, pc1, aC);
    }
    __syncthreads();
    const unsigned mask = selb_lds[qc];

    // ---- selection + window: 8 blocks per wave, full d ----
    f32x16 aS0 = {}, aS1 = {}, aW0 = {}, aW1 = {};
    float denS = 0.f, denW = 0.f;
    const int wlo = qt > 0 ? qt - 1 : 0;
    const int whi = qt < 31 ? qt + 1 : 31;

    int kra[4];
    #pragma unroll
    for (int ks = 0; ks < 4; ++ks)
        kra[ks] = wid * 4096 + ((qc * 128 + ks * 32 + hi * 16) ^ ((qc & 7) << 4));
    const int vbase = wid * 4096 + 16384;
    const int v00o = vbase + ((qc * 64 + hi * 16) ^ ((qc & 3) << 4));
    const int v01o = vbase + ((qc * 64 + 32 + hi * 16) ^ ((qc & 3) << 4));
    const int v10o = vbase + ((2048 + qc * 64 + hi * 16) ^ ((qc & 3) << 4));
    const int v11o = vbase + ((2048 + qc * 64 + 32 + hi * 16) ^ ((qc & 3) << 4));

    for (int t = 0; t < 8; ++t) {
        const int blk = blo + t;
        const char* base = smem + (t & 1) * 32768;
        if (t < 7) {
            stage((t + 1) & 1, blk + 1);
            asm volatile("s_waitcnt vmcnt(8)" ::: "memory");
        } else {
            asm volatile("s_waitcnt vmcnt(0)" ::: "memory");
        }
        short8 kf[4];
        #pragma unroll
        for (int ks = 0; ks < 4; ++ks)
            kf[ks] = *(const short8*)(base + kra[ks]);
        __builtin_amdgcn_s_setprio(1);
        f32x16 s = {};
        #pragma unroll
        for (int ks = 0; ks < 4; ++ks)
            s = MFMA32(kf[ks], qf[ks], s);
        __builtin_amdgcn_s_setprio(0);
        float e[16];
        #pragma unroll
        for (int r = 0; r < 16; ++r) e[r] = exp2f(s[r]);

        short8 v00 = *(const short8*)(base + v00o);
        short8 v01 = *(const short8*)(base + v01o);
        short8 v10 = *(const short8*)(base + v10o);
        short8 v11 = *(const short8*)(base + v11o);

        const bool selb = (mask >> blk) & 1u;
        const unsigned selm = selb ? 0xFFFFFFFFu : 0u;
        {
            float tt = 0.f;
            #pragma unroll
            for (int r = 0; r < 16; ++r) tt += e[r];
            denS += selb ? tt : 0.f;
        }
        short8 pb0, pb1;
        packswap(e, selm, pb0, pb1);
        __builtin_amdgcn_s_setprio(1);
        aS0 = MFMA32(v00, pb0, aS0);
        aS0 = MFMA32(v01, pb1, aS0);
        aS1 = MFMA32(v10, pb0, aS1);
        aS1 = MFMA32(v11, pb1, aS1);
        __builtin_amdgcn_s_setprio(0);

        if (blk >= wlo && blk <= whi) {
            float ew[16];
            float tt = 0.f;
            #pragma unroll
            for (int r = 0; r < 16; ++r) {
                int kr = (r & 3) + 8 * (r >> 2) + 4 * hi;
                int dd = blk * 32 + kr - qrow;
                ew[r] = (dd >= -32 && dd <= 32) ? e[r] : 0.f;
                tt += ew[r];
            }
            denW += tt;
            short8 pw0, pw1;
            packswap(ew, 0xFFFFFFFFu, pw0, pw1);
            aW0 = MFMA32(v00, pw0, aW0);
            aW0 = MFMA32(v01, pw1, aW0);
            aW1 = MFMA32(v10, pw0, aW1);
            aW1 = MFMA32(v11, pw1, aW1);
        }
    }
    __syncthreads();

    // ---- cross-wave combine over staging LDS (stride 85) ----
    float* cmb = (float*)smem;
    if (wid > 0) {
        float* dst = cmb + (size_t)(wid - 1) * (64 * 85) + lane * 85;
        #pragma unroll
        for (int i = 0; i < 16; ++i) { dst[i] = aS0[i]; dst[16 + i] = aS1[i]; }
        #pragma unroll
        for (int i = 0; i < 16; ++i) { dst[32 + i] = aW0[i]; dst[48 + i] = aW1[i]; }
        dst[64] = denS; dst[65] = denW;
        if (wid == 1) {
            #pragma unroll
            for (int i = 0; i < 16; ++i) dst[66 + i] = aC[i];
        }
    }
    __syncthreads();
    if (wid == 0) {
        #pragma unroll
        for (int w = 1; w < 4; ++w) {
            const float* src = cmb + (size_t)(w - 1) * (64 * 85) + lane * 85;
            #pragma unroll
            for (int i = 0; i < 16; ++i) { aS0[i] += src[i]; aS1[i] += src[16 + i]; }
            #pragma unroll
            for (int i = 0; i < 16; ++i) { aW0[i] += src[32 + i]; aW1[i] += src[48 + i]; }
            denS += src[64]; denW += src[65];
        }
        f32x16 aC1;
        const float* s1 = cmb + lane * 85;
        #pragma unroll
        for (int i = 0; i < 16; ++i) aC1[i] = s1[66 + i];
        denS += __shfl_xor(denS, 32);
        denW += __shfl_xor(denW, 32);
        const float rc = g0 / denc, rs = g1 / denS, rw = g2 / denW;
        u16* op = att + (size_t)(b * 1024 + qrow) * NDIM + h * 64;
        #pragma unroll
        for (int c4 = 0; c4 < 4; ++c4) {
            int d0 = c4 * 8 + hi * 4;
            s16x4 w0, w1;
            #pragma unroll
            for (int j = 0; j < 4; ++j) {
                w0[j] = (short)f2b(rc * aC[c4 * 4 + j]  + rs * aS0[c4 * 4 + j] + rw * aW0[c4 * 4 + j]);
                w1[j] = (short)f2b(rc * aC1[c4 * 4 + j] + rs * aS1[c4 * 4 + j] + rw * aW1[c4 * 4 + j]);
            }
            *(s16x4*)&op[d0] = w0;
            *(s16x4*)&op[d0 + 32] = w1;
        }
    }
}

// ---------------- host ----------------
extern "C" void kernel_launch(void* const* d_in, const int* in_sizes, int n_in,
                              void* d_out, int out_size, void* d_ws, size_t ws_size,
                              hipStream_t stream)
{
    const float* x0    = (const float*)d_in[0];
    const float* ln1_g = (const float*)d_in[1];
    const float* ln1_b = (const float*)d_in[2];
    const float* Wq    = (const float*)d_in[3];
    const float* Wk    = (const float*)d_in[4];
    const float* Wv    = (const float*)d_in[5];
    const float* Wg    = (const float*)d_in[6];
    const float* bg    = (const float*)d_in[7];
    const float* Wo    = (const float*)d_in[8];
    const float* bo    = (const float*)d_in[9];
    const float* ln2_g = (const float*)d_in[10];
    const float* ln2_b = (const float*)d_in[11];
    const float* W1    = (const float*)d_in[12];
    const float* b1    = (const float*)d_in[13];
    const float* W2    = (const float*)d_in[14];
    const float* b2    = (const float*)d_in[15];
    float* xo = (float*)d_out;

    char* w = (char*)d_ws;
    auto alloc = [&](size_t bytes) { char* p = w; w += (bytes + 255) & ~(size_t)255; return p; };
    u16*   hbf   = (u16*)  alloc((size_t)NROWS * NDIM * 2);
    u16*   qb    = (u16*)  alloc((size_t)NBH * NSEQ * NDH * 2);
    u16*   kb    = (u16*)  alloc((size_t)NBH * NSEQ * NDH * 2);
    u16*   vt    = (u16*)  alloc((size_t)NBH * NDH * NSEQ * 2);
    u16*   att   = (u16*)  alloc((size_t)NROWS * NDIM * 2);
    float* gates = (float*)alloc((size_t)NROWS * NHEAD * 3 * 4);
    u16*   kc16  = (u16*)  alloc((size_t)NBH * NBLKC * NDH * 2);
    u16*   vct16 = (u16*)  alloc((size_t)NBH * NDH * NBLKC * 2);
    u16*   wqkvT = (u16*)  alloc((size_t)2 * NQKV * 512 * 2);
    u16*   woT   = (u16*)  alloc((size_t)2 * 512 * 512 * 2);
    u16*   w1T   = (u16*)  alloc((size_t)2 * 2048 * 512 * 2);
    u16*   w2T   = (u16*)  alloc((size_t)2 * 512 * 2048 * 2);
    u16*   mid   = (u16*)qb;

    setup_weights<<<6152, 256, 0, stream>>>(Wq, Wk, Wv, Wg, Wo, W1, W2, wqkvT, woT, w1T, w2T);

    for (int l = 0; l < 2; ++l) {
        const float* xin = (l == 0) ? x0 : xo;   // residual source for this layer's attn block
        ln_kernel<<<NROWS / 4, 256, 0, stream>>>(xin, ln1_g + l * NDIM, ln1_b + l * NDIM, hbf);
        gemm_k<64, 128, 64, 512, EP_QKV><<<dim3(NQKV / 128, NROWS / 64), 256, 0, stream>>>(
            hbf, wqkvT + (size_t)l * NQKV * 512, NROWS, NQKV,
            bg + l * 24, nullptr, gates, nullptr, qb, kb, vt, kc16, vct16);
        attn_mfma<<<1024, 256, 0, stream>>>(qb, kb, vt, kc16, vct16, gates, att);
        gemm_k<64, 64, 64, 512, EP_RES><<<dim3(512 / 64, NROWS / 64), 256, 0, stream>>>(
            att, woT + (size_t)l * 512 * 512, NROWS, 512,
            bo + l * NDIM, xin, xo, nullptr, nullptr, nullptr, nullptr);
        ln_kernel<<<NROWS / 4, 256, 0, stream>>>(xo, ln2_g + l * NDIM, ln2_b + l * NDIM, hbf);
        gemm_k<64, 128, 64, 512, EP_GELU><<<dim3(2048 / 128, NROWS / 64), 256, 0, stream>>>(
            hbf, w1T + (size_t)l * 2048 * 512, NROWS, 2048,
            b1 + l * NMLP, nullptr, nullptr, mid, nullptr, nullptr, nullptr);
        gemm_k<64, 64, 64, 2048, EP_RES><<<dim3(512 / 64, NROWS / 64), 256, 0, stream>>>(
            mid, w2T + (size_t)l * 512 * 2048, NROWS, 512,
            b2 + l * NDIM, xo, xo, nullptr, nullptr, nullptr, nullptr);
    }
}